// Round 12
// baseline (255.118 us; speedup 1.0000x reference)
//
#include <hip/hip_runtime.h>
#include <hip/hip_bf16.h>

// MultiAttentionHead: B=2, T=2048, E=1024, H=16, D=64
// Inputs (fp32): x[B,T,E], Wq[H,E,D], Wk[H,E,D], Wv[H,E,D], Wo[E,E]
// Output (fp32): combined @ Wo + x   [B,T,E]
//
// ws layout (ushort=fp16 elements):
//   xh/comb : 0        .. 4M    (x fp16, later overwritten by attn output)
//   wt      : 4M       .. 7.34M ([p][h][d][e] transposed QKV weights)
//   wot     : 7.34M    .. 8.39M ([j][e] transposed Wo)
//   q : 8.39M  k : 12.58M  vt : 16.78M .. 21.24M  (total ~42.5 MB)
//
// Lessons: (r10/r11) fragment gathers whose adjacent lanes stride by the row
// pitch choke the per-CU address pipe -> stage tiles coalesced, read frags
// from LDS. (r12) LD_=72 rows give 8-way LDS bank conflicts on b128 frag
// reads -> XOR-swizzle 16B chunks within 64-elem rows, conflict-free.
// q is pre-scaled by 0.125*log2(e) so attn uses exp2f with zero extra muls.

#define B_ 2
#define T_ 2048
#define E_ 1024
#define H_ 16
#define D_ 64
#define VTS_ 2176   // padded vt leading dim (elements)
#define LD_ 72      // LDS row stride for GEMM staging kernels (validated r11)

typedef _Float16 h8 __attribute__((ext_vector_type(8)));
typedef float f32x4 __attribute__((ext_vector_type(4)));

union U4 { uint4 u; h8 h; };

__device__ __forceinline__ float h2f(unsigned short s) {
  _Float16 h;
  __builtin_memcpy(&h, &s, 2);
  return (float)h;
}

__device__ __forceinline__ unsigned short f2h(float f) {
  _Float16 h = (_Float16)f;
  unsigned short s;
  __builtin_memcpy(&s, &h, 2);
  return s;
}

// DPP cross-lane move within a 16-lane row (full-rate VALU, no LDS pipe).
template <int CTRL>
__device__ __forceinline__ float dppmv(float x) {
  union { float f; int i; } c;
  c.f = x;
  c.i = __builtin_amdgcn_mov_dpp(c.i, CTRL, 0xF, 0xF, true);
  return c.f;
}

__device__ __forceinline__ float rowmax16(float x) {
  x = fmaxf(x, dppmv<0xB1>(x));   // lane^1
  x = fmaxf(x, dppmv<0x4E>(x));   // lane^2
  x = fmaxf(x, dppmv<0x141>(x));  // row_half_mirror
  x = fmaxf(x, dppmv<0x140>(x));  // row_mirror
  return x;
}

__device__ __forceinline__ float rowsum16(float x) {
  x += dppmv<0xB1>(x);
  x += dppmv<0x4E>(x);
  x += dppmv<0x141>(x);
  x += dppmv<0x140>(x);
  return x;
}

// ---------------------------------------------------------------------------
// Prep 0: x fp32 -> fp16.  grid = B*T*E/1024, block=256.
// ---------------------------------------------------------------------------
__global__ __launch_bounds__(256) void cvt_x(const float* __restrict__ x,
                                             unsigned short* __restrict__ xh) {
  const size_t i = ((size_t)blockIdx.x * 256 + threadIdx.x) * 4;
  const float4 f = *(const float4*)(x + i);
  ushort4 pk;
  pk.x = f2h(f.x); pk.y = f2h(f.y); pk.z = f2h(f.z); pk.w = f2h(f.w);
  *(ushort4*)(xh + i) = pk;
}

// ---------------------------------------------------------------------------
// Prep 1: Wq/Wk/Wv [h][e][d] fp32 -> wt [p][h][d][e] fp16. grid=(16,16,3).
// ---------------------------------------------------------------------------
__global__ __launch_bounds__(256) void tconv_w(
    const float* __restrict__ Wq, const float* __restrict__ Wk,
    const float* __restrict__ Wv, unsigned short* __restrict__ wt) {
  __shared__ float ts[64][65];
  const int p = blockIdx.z, h = blockIdx.y;
  const float* src = ((p == 0) ? Wq : (p == 1) ? Wk : Wv) + (size_t)h * E_ * D_;
  unsigned short* dst = wt + (size_t)(p * H_ + h) * D_ * E_;
  const int r0 = blockIdx.x * 64;  // e-tile
  const int lr = threadIdx.x >> 4, lc = (threadIdx.x & 15) * 4;
#pragma unroll
  for (int it = 0; it < 4; it++) {
    const float4 f = *(const float4*)(src + (size_t)(r0 + lr + it * 16) * D_ + lc);
    ts[lr + it * 16][lc] = f.x; ts[lr + it * 16][lc + 1] = f.y;
    ts[lr + it * 16][lc + 2] = f.z; ts[lr + it * 16][lc + 3] = f.w;
  }
  __syncthreads();
#pragma unroll
  for (int it = 0; it < 4; it++) {
    const int dr = lr + it * 16;  // d
    ushort4 pk;
    pk.x = f2h(ts[lc + 0][dr]); pk.y = f2h(ts[lc + 1][dr]);
    pk.z = f2h(ts[lc + 2][dr]); pk.w = f2h(ts[lc + 3][dr]);
    *(ushort4*)(dst + (size_t)dr * E_ + r0 + lc) = pk;
  }
}

// ---------------------------------------------------------------------------
// Prep 2: Wo [e][j] fp32 -> wot [j][e] fp16. grid=(16,16).
// ---------------------------------------------------------------------------
__global__ __launch_bounds__(256) void tconv_wo(const float* __restrict__ Wo,
                                                unsigned short* __restrict__ wot) {
  __shared__ float ts[64][65];
  const int r0 = blockIdx.x * 64;  // e-tile
  const int c0 = blockIdx.y * 64;  // j-tile
  const int lr = threadIdx.x >> 4, lc = (threadIdx.x & 15) * 4;
#pragma unroll
  for (int it = 0; it < 4; it++) {
    const float4 f = *(const float4*)(Wo + (size_t)(r0 + lr + it * 16) * E_ + c0 + lc);
    ts[lr + it * 16][lc] = f.x; ts[lr + it * 16][lc + 1] = f.y;
    ts[lr + it * 16][lc + 2] = f.z; ts[lr + it * 16][lc + 3] = f.w;
  }
  __syncthreads();
#pragma unroll
  for (int it = 0; it < 4; it++) {
    const int dr = lr + it * 16;  // j within tile
    ushort4 pk;
    pk.x = f2h(ts[lc + 0][dr]); pk.y = f2h(ts[lc + 1][dr]);
    pk.z = f2h(ts[lc + 2][dr]); pk.w = f2h(ts[lc + 3][dr]);
    *(ushort4*)(wot + (size_t)(c0 + dr) * E_ + r0 + lc) = pk;
  }
}

// ---------------------------------------------------------------------------
// Kernel 1: QKV projections via MFMA, coalesced LDS staging (validated r11).
// grid=(B*T/128, H, 3), block=256.  q output pre-scaled by 0.125*log2(e).
// ---------------------------------------------------------------------------
__global__ __launch_bounds__(256) void qkv_mfma(
    const unsigned short* __restrict__ xh, const unsigned short* __restrict__ wt,
    unsigned short* __restrict__ qo, unsigned short* __restrict__ ko,
    unsigned short* __restrict__ vo)
{
  __shared__ unsigned short xs[128 * LD_];   // [token][e]
  __shared__ unsigned short wsb[64 * LD_];   // [d][e]
  __shared__ unsigned short Cl[4][32 * 72];  // per-wave repack tile

  const int tid = threadIdx.x;
  const int w = tid >> 6, lane = tid & 63;
  const int m16 = lane & 15, quad = lane >> 4;
  const int h = blockIdx.y, p = blockIdx.z;
  const int n0 = blockIdx.x * 128;           // block token base
  const unsigned short* wb = wt + (size_t)(p * H_ + h) * D_ * E_;

  const int sr = tid >> 3;          // 0..31
  const int sc = (tid & 7) * 8;     // 0,8,...,56

  f32x4 acc[2][4];
#pragma unroll
  for (int rt = 0; rt < 2; rt++)
#pragma unroll
    for (int ct = 0; ct < 4; ct++) acc[rt][ct] = (f32x4){0.f, 0.f, 0.f, 0.f};

  for (int e0 = 0; e0 < E_; e0 += 64) {
    __syncthreads();
#pragma unroll
    for (int it = 0; it < 4; it++) {
      const int row = it * 32 + sr;
      *(uint4*)(xs + row * LD_ + sc) =
          *(const uint4*)(xh + (size_t)(n0 + row) * E_ + e0 + sc);
    }
#pragma unroll
    for (int it = 0; it < 2; it++) {
      const int row = it * 32 + sr;
      *(uint4*)(wsb + row * LD_ + sc) =
          *(const uint4*)(wb + (size_t)row * E_ + e0 + sc);
    }
    __syncthreads();

#pragma unroll
    for (int kk = 0; kk < 64; kk += 32) {
      U4 a0, a1, bf[4];
      a0.u = *(const uint4*)(xs + (w * 32 + m16) * LD_ + kk + quad * 8);
      a1.u = *(const uint4*)(xs + (w * 32 + 16 + m16) * LD_ + kk + quad * 8);
#pragma unroll
      for (int ct = 0; ct < 4; ct++)
        bf[ct].u = *(const uint4*)(wsb + (ct * 16 + m16) * LD_ + kk + quad * 8);
#pragma unroll
      for (int ct = 0; ct < 4; ct++) {
        acc[0][ct] = __builtin_amdgcn_mfma_f32_16x16x32_f16(a0.h, bf[ct].h, acc[0][ct], 0, 0, 0);
        acc[1][ct] = __builtin_amdgcn_mfma_f32_16x16x32_f16(a1.h, bf[ct].h, acc[1][ct], 0, 0, 0);
      }
    }
  }

  const int nw = n0 + w * 32;               // wave token base
  const int b  = n0 >> 11;                  // batch (128 | 2048, never straddles)
  const int t0 = nw & (T_ - 1);
  const size_t bh = (size_t)(b * H_ + h);

  if (p == 2) {
#pragma unroll
    for (int rt = 0; rt < 2; rt++)
#pragma unroll
      for (int ct = 0; ct < 4; ct++) {
        const int d = ct * 16 + m16;
        const int t = t0 + rt * 16 + quad * 4;
        ushort4 pk;
        pk.x = f2h(acc[rt][ct][0]); pk.y = f2h(acc[rt][ct][1]);
        pk.z = f2h(acc[rt][ct][2]); pk.w = f2h(acc[rt][ct][3]);
        *(ushort4*)(vo + (bh * D_ + d) * (size_t)VTS_ + t) = pk;
      }
  } else {
    // q is pre-scaled so attn scores are in log2 domain: 1/sqrt(64)*log2(e)
    const float qs = (p == 0) ? 0.18033688f : 1.0f;
    unsigned short* outp = (p == 0) ? qo : ko;
    unsigned short* Cw = &Cl[w][0];
#pragma unroll
    for (int rt = 0; rt < 2; rt++)
#pragma unroll
      for (int ct = 0; ct < 4; ct++)
#pragma unroll
        for (int r = 0; r < 4; r++)
          Cw[(rt * 16 + quad * 4 + r) * 72 + ct * 16 + m16] = f2h(acc[rt][ct][r] * qs);
    const int row = lane >> 1;
    const int half = (lane & 1) * 32;
    const uint4 d0 = *(const uint4*)(Cw + row * 72 + half);
    const uint4 d1 = *(const uint4*)(Cw + row * 72 + half + 8);
    const uint4 d2 = *(const uint4*)(Cw + row * 72 + half + 16);
    const uint4 d3 = *(const uint4*)(Cw + row * 72 + half + 24);
    unsigned short* dst = outp + (bh * T_ + t0 + row) * D_ + half;
    *(uint4*)(dst)      = d0;
    *(uint4*)(dst + 8)  = d1;
    *(uint4*)(dst + 16) = d2;
    *(uint4*)(dst + 24) = d3;
  }
}

// ---------------------------------------------------------------------------
// Kernel 2: MFMA flash attention — coalesced staging + XOR-swizzled LDS.
// grid=(T/64, H, B), block=256 (4 waves = 4 Q-tiles of 16 rows).
// LDS rows are 64 elems = 8 chunks of 16B; chunk c of row r lives at
// physical chunk c ^ (r&7)  -> conflict-free b128 staging AND frag reads.
// Scores arrive in log2 domain (q pre-scaled) -> exp2f, no muls.
// ---------------------------------------------------------------------------
__global__ __launch_bounds__(256) void attn_kernel(
    const unsigned short* __restrict__ q, const unsigned short* __restrict__ k,
    const unsigned short* __restrict__ vt, unsigned short* __restrict__ comb)
{
  __shared__ unsigned short Kt[64 * 64];   // [key][d], swizzled
  __shared__ unsigned short Vt[64 * 64];   // [d][key], swizzled
  __shared__ unsigned short Pl[4][16 * 64];// per-wave P, swizzled

  const int tid  = threadIdx.x;
  const int w    = tid >> 6;
  const int lane = tid & 63;
  const int m16  = lane & 15;
  const int quad = lane >> 4;
  const int h = blockIdx.y, b = blockIdx.z;
  const size_t bh = (size_t)(b * H_ + h);
  const int q0 = blockIdx.x * 64 + w * 16;

  U4 aQ0, aQ1;
  {
    const unsigned short* qrow = q + (bh * T_ + q0 + m16) * (size_t)D_;
    aQ0.u = *(const uint4*)(qrow + quad * 8);
    aQ1.u = *(const uint4*)(qrow + 32 + quad * 8);
  }

  f32x4 o0 = {0.f, 0.f, 0.f, 0.f}, o1 = o0, o2 = o0, o3 = o0;
  float mrow[4] = {-1e30f, -1e30f, -1e30f, -1e30f};
  float lrow[4] = {0.f, 0.f, 0.f, 0.f};

  const unsigned short* kb  = k  + bh * (size_t)(T_ * D_);
  const unsigned short* vtb = vt + bh * (size_t)(D_ * VTS_);
  unsigned short* Pw = &Pl[w][0];

  const int sr = tid >> 3;          // 0..31
  const int sj = tid & 7;           // chunk index 0..7
  const int swz = (sj ^ (sr & 7)) << 3;   // swizzled chunk offset (elements)

  for (int kt = 0; kt < T_; kt += 64) {
    __syncthreads();
    {
      const uint4 ka = *(const uint4*)(kb + (size_t)(kt + sr) * D_ + sj * 8);
      const uint4 kc = *(const uint4*)(kb + (size_t)(kt + 32 + sr) * D_ + sj * 8);
      *(uint4*)(Kt + sr * 64 + swz)        = ka;
      *(uint4*)(Kt + (32 + sr) * 64 + swz) = kc;
      const uint4 va = *(const uint4*)(vtb + (size_t)sr * VTS_ + kt + sj * 8);
      const uint4 vc = *(const uint4*)(vtb + (size_t)(32 + sr) * VTS_ + kt + sj * 8);
      *(uint4*)(Vt + sr * 64 + swz)        = va;
      *(uint4*)(Vt + (32 + sr) * 64 + swz) = vc;
    }
    __syncthreads();

    // ---- S = Q K^T over 4 key sub-tiles of 16 ----
    f32x4 s[4];
#pragma unroll
    for (int ct = 0; ct < 4; ct++) {
      const int row = ct * 16 + m16;
      const int rx = row & 7;
      U4 kf0, kf1;
      kf0.u = *(const uint4*)(Kt + row * 64 + ((quad ^ rx) << 3));
      kf1.u = *(const uint4*)(Kt + row * 64 + (((4 + quad) ^ rx) << 3));
      f32x4 z = {0.f, 0.f, 0.f, 0.f};
      z = __builtin_amdgcn_mfma_f32_16x16x32_f16(aQ0.h, kf0.h, z, 0, 0, 0);
      z = __builtin_amdgcn_mfma_f32_16x16x32_f16(aQ1.h, kf1.h, z, 0, 0, 0);
      s[ct] = z;
    }

    // ---- online softmax over 64 keys (log2 domain, DPP reductions) ----
    float al[4];
#pragma unroll
    for (int r = 0; r < 4; r++) {
      const float s0 = s[0][r];
      const float s1 = s[1][r];
      const float s2 = s[2][r];
      const float s3 = s[3][r];
      const float mt = rowmax16(fmaxf(fmaxf(s0, s1), fmaxf(s2, s3)));
      const float mn = fmaxf(mrow[r], mt);
      const float a  = exp2f(mrow[r] - mn);
      const float p0 = exp2f(s0 - mn);
      const float p1 = exp2f(s1 - mn);
      const float p2 = exp2f(s2 - mn);
      const float p3 = exp2f(s3 - mn);
      const float rs = rowsum16(p0 + p1 + p2 + p3);
      lrow[r] = lrow[r] * a + rs;
      mrow[r] = mn;
      al[r] = a;
      const int pr = quad * 4 + r;
      const int prx = pr & 7, hi = m16 >> 3, lo = m16 & 7;
      unsigned short* Prow = Pw + pr * 64;
      Prow[(((0 + hi) ^ prx) << 3) + lo] = f2h(p0);
      Prow[(((2 + hi) ^ prx) << 3) + lo] = f2h(p1);
      Prow[(((4 + hi) ^ prx) << 3) + lo] = f2h(p2);
      Prow[(((6 + hi) ^ prx) << 3) + lo] = f2h(p3);
    }

#pragma unroll
    for (int r = 0; r < 4; r++) {
      o0[r] *= al[r]; o1[r] *= al[r]; o2[r] *= al[r]; o3[r] *= al[r];
    }

    // ---- P: C-layout -> A-layout via per-wave LDS (same-wave, in-order) ----
    const int mx = m16 & 7;
    U4 aP0, aP1;
    aP0.u = *(const uint4*)(Pw + m16 * 64 + ((quad ^ mx) << 3));
    aP1.u = *(const uint4*)(Pw + m16 * 64 + (((4 + quad) ^ mx) << 3));

    // ---- PV: 2 key-chunks x 4 d-tiles ----
#pragma unroll
    for (int ct = 0; ct < 4; ct++) {
      const int row = ct * 16 + m16;
      const int rx = row & 7;
      U4 vf0, vf1;
      vf0.u = *(const uint4*)(Vt + row * 64 + ((quad ^ rx) << 3));
      vf1.u = *(const uint4*)(Vt + row * 64 + (((4 + quad) ^ rx) << 3));
      f32x4* op = (ct == 0) ? &o0 : (ct == 1) ? &o1 : (ct == 2) ? &o2 : &o3;
      *op = __builtin_amdgcn_mfma_f32_16x16x32_f16(aP0.h, vf0.h, *op, 0, 0, 0);
      *op = __builtin_amdgcn_mfma_f32_16x16x32_f16(aP1.h, vf1.h, *op, 0, 0, 0);
    }
  }

  // ---- epilogue: O /= l, store fp16 to comb[b][t][h*64 + d] ----
#pragma unroll
  for (int r = 0; r < 4; r++) {
    const float inv = 1.f / lrow[r];
    const int t = q0 + quad * 4 + r;
    unsigned short* dst = comb + ((size_t)b * T_ + t) * E_ + h * D_;
    dst[m16]      = f2h(o0[r] * inv);
    dst[16 + m16] = f2h(o1[r] * inv);
    dst[32 + m16] = f2h(o2[r] * inv);
    dst[48 + m16] = f2h(o3[r] * inv);
  }
}

// ---------------------------------------------------------------------------
// Kernel 3: out = comb @ Wo + x, coalesced LDS staging (validated r11).
// grid=(B*T/128, E/64), block=256 (4 waves). Block: 128 n x 64 j.
// ---------------------------------------------------------------------------
__global__ __launch_bounds__(256) void out_mfma(
    const unsigned short* __restrict__ comb, const unsigned short* __restrict__ wot,
    const float* __restrict__ x, float* __restrict__ out)
{
  __shared__ unsigned short cs[128 * LD_];   // [n][e]
  __shared__ unsigned short wsb[64 * LD_];   // [j][e]

  const int tid = threadIdx.x;
  const int w = tid >> 6, lane = tid & 63;
  const int m16 = lane & 15, quad = lane >> 4;
  const int n0 = blockIdx.x * 128;
  const int j0 = blockIdx.y * 64;

  const int sr = tid >> 3;          // 0..31
  const int sc = (tid & 7) * 8;     // 0,8,...,56

  f32x4 acc[2][4];
#pragma unroll
  for (int rt = 0; rt < 2; rt++)
#pragma unroll
    for (int ct = 0; ct < 4; ct++) acc[rt][ct] = (f32x4){0.f, 0.f, 0.f, 0.f};

  for (int e0 = 0; e0 < E_; e0 += 64) {
    __syncthreads();
#pragma unroll
    for (int it = 0; it < 4; it++) {
      const int row = it * 32 + sr;
      *(uint4*)(cs + row * LD_ + sc) =
          *(const uint4*)(comb + (size_t)(n0 + row) * E_ + e0 + sc);
    }
#pragma unroll
    for (int it = 0; it < 2; it++) {
      const int row = it * 32 + sr;
      *(uint4*)(wsb + row * LD_ + sc) =
          *(const uint4*)(wot + (size_t)(j0 + row) * E_ + e0 + sc);
    }
    __syncthreads();

#pragma unroll
    for (int kk = 0; kk < 64; kk += 32) {
      U4 a0, a1, bf[4];
      a0.u = *(const uint4*)(cs + (w * 32 + m16) * LD_ + kk + quad * 8);
      a1.u = *(const uint4*)(cs + (w * 32 + 16 + m16) * LD_ + kk + quad * 8);
#pragma unroll
      for (int ct = 0; ct < 4; ct++)
        bf[ct].u = *(const uint4*)(wsb + (ct * 16 + m16) * LD_ + kk + quad * 8);
#pragma unroll
      for (int ct = 0; ct < 4; ct++) {
        acc[0][ct] = __builtin_amdgcn_mfma_f32_16x16x32_f16(a0.h, bf[ct].h, acc[0][ct], 0, 0, 0);
        acc[1][ct] = __builtin_amdgcn_mfma_f32_16x16x32_f16(a1.h, bf[ct].h, acc[1][ct], 0, 0, 0);
      }
    }
  }

  const int nw = n0 + w * 32;
#pragma unroll
  for (int rt = 0; rt < 2; rt++)
#pragma unroll
    for (int r = 0; r < 4; r++) {
      const int n = nw + rt * 16 + quad * 4 + r;
      const float* xr = x + (size_t)n * E_ + j0;
      float* orow = out + (size_t)n * E_ + j0;
#pragma unroll
      for (int ct = 0; ct < 4; ct++) {
        const int j = ct * 16 + m16;
        orow[j] = acc[rt][ct][r] + xr[j];
      }
    }
}

// ---------------------------------------------------------------------------
extern "C" void kernel_launch(void* const* d_in, const int* in_sizes, int n_in,
                              void* d_out, int out_size, void* d_ws, size_t ws_size,
                              hipStream_t stream) {
  (void)in_sizes; (void)n_in; (void)out_size; (void)ws_size;

  const float* x  = (const float*)d_in[0];
  const float* Wq = (const float*)d_in[1];
  const float* Wk = (const float*)d_in[2];
  const float* Wv = (const float*)d_in[3];
  const float* Wo = (const float*)d_in[4];
  float* out = (float*)d_out;

  unsigned short* ws0  = (unsigned short*)d_ws;
  unsigned short* xh   = ws0;                    // 4M elems (aliases comb)
  unsigned short* wt   = ws0 + 4194304;          // 3M
  unsigned short* wot  = ws0 + 7340032;          // 1M
  unsigned short* qh   = ws0 + 8388608;          // 4M
  unsigned short* kh   = ws0 + 12582912;         // 4M
  unsigned short* vth  = ws0 + 16777216;         // 32*64*2176 = 4.46M (padded)
  unsigned short* comb = xh;                     // alias: xh dead after qkv

  cvt_x<<<dim3(B_ * T_ * E_ / 1024), dim3(256), 0, stream>>>(x, xh);
  tconv_w<<<dim3(E_ / 64, H_, 3), dim3(256), 0, stream>>>(Wq, Wk, Wv, wt);
  tconv_wo<<<dim3(E_ / 64, E_ / 64), dim3(256), 0, stream>>>(Wo, wot);

  qkv_mfma<<<dim3(B_ * T_ / 128, H_, 3), dim3(256), 0, stream>>>(xh, wt, qh, kh, vth);

  attn_kernel<<<dim3(T_ / 64, H_, B_), dim3(256), 0, stream>>>(qh, kh, vth, comb);

  out_mfma<<<dim3(B_ * T_ / 128, E_ / 64), dim3(256), 0, stream>>>(comb, wot, x, out);
}